// Round 7
// baseline (105.832 us; speedup 1.0000x reference)
//
#include <hip/hip_runtime.h>
#include <hip/hip_bf16.h>
#include <stdint.h>

#define NROWS 8192
#define BROWS 4096
#define SQRT_SCALE 3.7982826f   // sqrt((1/T)*log2(e)), T=0.1
#define LN2 0.6931471805599453f
#define NBLK 544                // sum_{it=0}^{63} ceil((8192-128it)/512)

typedef __attribute__((ext_vector_type(8))) short bf16x8;
typedef __attribute__((ext_vector_type(4))) float f32x4;

__device__ inline unsigned short f2bf(float x) {
  __hip_bfloat16 h = __float2bfloat16(x);
  return __builtin_bit_cast(unsigned short, h);
}

// Kernel A: L2-normalize rows, scale by sqrt((1/T)log2e), -> bf16 reps; zero denom/out.
__global__ __launch_bounds__(256) void knorm(const float* __restrict__ zi,
                                             const float* __restrict__ zj,
                                             unsigned short* __restrict__ reps,
                                             float* __restrict__ denom,
                                             float* __restrict__ out) {
  int w = threadIdx.x >> 6, l = threadIdx.x & 63;
  int row = blockIdx.x * 4 + w;
  const float* src = (row < BROWS) ? (zi + (size_t)row * 256)
                                   : (zj + (size_t)(row - BROWS) * 256);
  float4 v = ((const float4*)src)[l];
  float ss = v.x * v.x + v.y * v.y + v.z * v.z + v.w * v.w;
#pragma unroll
  for (int m = 1; m < 64; m <<= 1) ss += __shfl_xor(ss, m, 64);
  float sc = SQRT_SCALE / fmaxf(sqrtf(ss), 1e-12f);
  ushort4 o;
  o.x = f2bf(v.x * sc); o.y = f2bf(v.y * sc);
  o.z = f2bf(v.z * sc); o.w = f2bf(v.w * sc);
  ((ushort4*)reps)[(size_t)row * 64 + l] = o;
  if (l == 0) denom[row] = 0.f;
  if (row == 0 && l == 0) out[0] = 0.f;
}

// Kernel B: barrier-free upper-tri sim. reps (4 MB) is L2-resident, and the
// MFMA B-fragment layout equals the A layout (row-major 16B/lane), so B-frags
// load straight from global -- no LDS staging, no barriers, waves independent.
// Block = (128-row strip it, 512-col chunk q); 4 waves x 32 rows; 32-col steps.
__global__ __launch_bounds__(256, 3) void ksim(const unsigned short* __restrict__ reps_,
                                               float* __restrict__ denom,
                                               float* __restrict__ pos) {
  __shared__ float colacc[4][512];   // per-wave column accumulators, 8 KB
  const uint4* reps4 = (const uint4*)reps_;
  int tid = threadIdx.x, w = tid >> 6, l = tid & 63;
  int kgrp = l >> 4;

  // ---- block -> (strip it, chunk q); chunks(it) = ceil((64-it)/4), total 544 ----
  int rem = blockIdx.x, it = 0, ch;
  while (rem >= (ch = (64 - it + 3) >> 2)) { rem -= ch; ++it; }
  int q = rem;
  int rowbase = it * 128;
  int cs0 = rowbase + q * 512;
  int niter = (NROWS - cs0) >> 5; if (niter > 16) niter = 16;

  // ---- zero colacc ----
#pragma unroll
  for (int i = 0; i < 8; ++i) ((float*)colacc)[tid + 256 * i] = 0.f;

  // ---- A fragments: wave w owns rows rowbase+32w..+32; lane holds row
  //      +fr*16+(l&15), k bytes [kk*64 + kgrp*16, +16) ----
  bf16x8 a[2][8];
  int arow = rowbase + w * 32 + (l & 15);
#pragma unroll
  for (int fr = 0; fr < 2; ++fr) {
    const uint4* base = reps4 + (size_t)(arow + fr * 16) * 32 + kgrp;
#pragma unroll
    for (int kk = 0; kk < 8; ++kk)
      a[fr][kk] = __builtin_bit_cast(bf16x8, base[kk * 4]);
  }

  float rowsum[2][4];
#pragma unroll
  for (int fr = 0; fr < 2; ++fr)
#pragma unroll
    for (int r = 0; r < 4; ++r) rowsum[fr][r] = 0.f;

  bool posChunk = (q == 8) && (it < 32);
  int r0 = rowbase + w * 32 + kgrp * 4;

  for (int t = 0; t < niter; ++t) {
    int cb = cs0 + 32 * t;
    // B-fragment pointers: lane l -> reps row (cb + (l&15)) [+16], 16B chunk kgrp.
    const uint4* bp0 = reps4 + (size_t)(cb + (l & 15)) * 32 + kgrp;
    const uint4* bp1 = bp0 + 16 * 32;

    f32x4 acc[2][2];
    const f32x4 zero = {0.f, 0.f, 0.f, 0.f};
#pragma unroll
    for (int kk = 0; kk < 8; ++kk) {
      bf16x8 b0 = __builtin_bit_cast(bf16x8, bp0[kk * 4]);
      bf16x8 b1 = __builtin_bit_cast(bf16x8, bp1[kk * 4]);
#pragma unroll
      for (int fr = 0; fr < 2; ++fr) {
        if (kk == 0) {
          acc[fr][0] = __builtin_amdgcn_mfma_f32_16x16x32_bf16(a[fr][0], b0, zero, 0, 0, 0);
          acc[fr][1] = __builtin_amdgcn_mfma_f32_16x16x32_bf16(a[fr][0], b1, zero, 0, 0, 0);
        } else {
          acc[fr][0] = __builtin_amdgcn_mfma_f32_16x16x32_bf16(a[fr][kk], b0, acc[fr][0], 0, 0, 0);
          acc[fr][1] = __builtin_amdgcn_mfma_f32_16x16x32_bf16(a[fr][kk], b1, acc[fr][1], 0, 0, 0);
        }
      }
    }

    // ---- epilogue: e=exp2(acc), diag mask, rowsum + col partials ----
    bool docol = !(q == 0 && t < 4);       // diag 128-col window: rowsum only
    bool dopos = posChunk && (t < 4);
    float cp0 = 0.f, cp1 = 0.f;
    int cbase = cb + (l & 15);
#pragma unroll
    for (int fr = 0; fr < 2; ++fr)
#pragma unroll
      for (int fc = 0; fc < 2; ++fc)
#pragma unroll
        for (int r = 0; r < 4; ++r) {
          int rg = r0 + fr * 16 + r;
          int cg = cbase + fc * 16;
          float s = acc[fr][fc][r];
          float e = __builtin_amdgcn_exp2f(s);
          e = (rg == cg) ? 0.f : e;
          if (dopos && cg == rg + BROWS) pos[rg] = s;
          rowsum[fr][r] += e;
          if (fc == 0) cp0 += e; else cp1 += e;
        }
    if (docol) {
      cp0 += __shfl_xor(cp0, 16, 64); cp0 += __shfl_xor(cp0, 32, 64);
      cp1 += __shfl_xor(cp1, 16, 64); cp1 += __shfl_xor(cp1, 32, 64);
      if (l < 16) {
        int off = (cb - cs0) + l;
        colacc[w][off] += cp0;
        colacc[w][off + 16] += cp1;
      }
    }
  }

  // ---- row sums: reduce 16 col-lanes; 4 lanes atomic per wave ----
#pragma unroll
  for (int fr = 0; fr < 2; ++fr)
#pragma unroll
    for (int r = 0; r < 4; ++r) {
      float v = rowsum[fr][r];
      v += __shfl_xor(v, 1, 64);
      v += __shfl_xor(v, 2, 64);
      v += __shfl_xor(v, 4, 64);
      v += __shfl_xor(v, 8, 64);
      if ((l & 15) == 0) atomicAdd(&denom[r0 + fr * 16 + r], v);
    }

  // ---- col sums: combine 4 wave regions, one atomic per column ----
  __syncthreads();
#pragma unroll
  for (int i = 0; i < 2; ++i) {
    int off = tid + 256 * i;
    float v = colacc[0][off & 511] + colacc[1][off & 511] +
              colacc[2][off & 511] + colacc[3][off & 511];
    int col = cs0 + off;
    if (col < NROWS && v != 0.f) atomicAdd(&denom[col], v);
  }
}

// Kernel F: + (1/N) * sum_i (log(denom_i) - posS_{i mod B} * ln2)
__global__ __launch_bounds__(256) void kfin(const float* __restrict__ denom,
                                            const float* __restrict__ pos,
                                            float* __restrict__ out) {
  int i = blockIdx.x * 256 + threadIdx.x;
  float v = (logf(denom[i]) - pos[i & 4095] * LN2) * (1.0f / 8192.0f);
#pragma unroll
  for (int m = 1; m < 64; m <<= 1) v += __shfl_xor(v, m, 64);
  __shared__ float part[4];
  if ((threadIdx.x & 63) == 0) part[threadIdx.x >> 6] = v;
  __syncthreads();
  if (threadIdx.x == 0)
    atomicAdd(out, part[0] + part[1] + part[2] + part[3]);
}

extern "C" void kernel_launch(void* const* d_in, const int* in_sizes, int n_in,
                              void* d_out, int out_size, void* d_ws, size_t ws_size,
                              hipStream_t stream) {
  (void)in_sizes; (void)n_in; (void)out_size; (void)ws_size;
  const float* zi = (const float*)d_in[0];
  const float* zj = (const float*)d_in[1];
  float* out = (float*)d_out;
  char* ws = (char*)d_ws;
  unsigned short* reps = (unsigned short*)ws;                 // 4 MB
  float* denom = (float*)(ws + 4194304);                      // 32 KB
  float* pos   = (float*)(ws + 4194304 + 32768);              // 16 KB

  knorm<<<2048, 256, 0, stream>>>(zi, zj, reps, denom, out);
  ksim<<<NBLK, 256, 0, stream>>>(reps, denom, pos);
  kfin<<<32, 256, 0, stream>>>(denom, pos, out);
}

// Round 8
// 54.310 us; speedup vs baseline: 1.9486x; 1.9486x over previous
//
#include <hip/hip_runtime.h>
#include <hip/hip_bf16.h>
#include <stdint.h>

#define NROWS 8192
#define BROWS 4096
#define SQRT_SCALE 3.7982826f   // sqrt((1/T)*log2(e)), T=0.1
#define LN2 0.6931471805599453f
#define NBLK 715                // sum_{it=0}^{63} ceil((64-it)/3)

typedef __attribute__((ext_vector_type(8))) short bf16x8;
typedef __attribute__((ext_vector_type(4))) float f32x4;

__device__ inline void gload_lds16(const void* g, void* l) {
  __builtin_amdgcn_global_load_lds((const __attribute__((address_space(1))) void*)g,
                                   (__attribute__((address_space(3))) void*)l,
                                   16, 0, 0);
}

__device__ inline unsigned short f2bf(float x) {
  __hip_bfloat16 h = __float2bfloat16(x);
  return __builtin_bit_cast(unsigned short, h);
}

// Kernel A: L2-normalize rows, scale by sqrt((1/T)log2e), -> bf16 reps; zero denom/out.
__global__ __launch_bounds__(256) void knorm(const float* __restrict__ zi,
                                             const float* __restrict__ zj,
                                             unsigned short* __restrict__ reps,
                                             float* __restrict__ denom,
                                             float* __restrict__ out) {
  int w = threadIdx.x >> 6, l = threadIdx.x & 63;
  int row = blockIdx.x * 4 + w;
  const float* src = (row < BROWS) ? (zi + (size_t)row * 256)
                                   : (zj + (size_t)(row - BROWS) * 256);
  float4 v = ((const float4*)src)[l];
  float ss = v.x * v.x + v.y * v.y + v.z * v.z + v.w * v.w;
#pragma unroll
  for (int m = 1; m < 64; m <<= 1) ss += __shfl_xor(ss, m, 64);
  float sc = SQRT_SCALE / fmaxf(sqrtf(ss), 1e-12f);
  ushort4 o;
  o.x = f2bf(v.x * sc); o.y = f2bf(v.y * sc);
  o.z = f2bf(v.z * sc); o.w = f2bf(v.w * sc);
  ((ushort4*)reps)[(size_t)row * 64 + l] = o;
  if (l == 0) denom[row] = 0.f;
  if (row == 0 && l == 0) out[0] = 0.f;
}

// Kernel B: strip-streaming upper-tri sim. Ring-3 LDS, depth-2 prefetch,
// ONE barrier per 32-col step, counted vmcnt(4), acc ping-pong epilogue overlap.
// Block = (128-row strip it, 384-col chunk q); 4 waves x 32 rows.
__global__ __launch_bounds__(256, 3) void ksim(const unsigned short* __restrict__ reps_,
                                               float* __restrict__ denom,
                                               float* __restrict__ pos) {
  __shared__ uint4 smem[3][1024];    // 3 x 32 rows x 512 B = 48 KB ring
  __shared__ float colacc[384];      // ds_add_f32 column accumulators
  const uint4* reps4 = (const uint4*)reps_;
  int tid = threadIdx.x, w = tid >> 6, l = tid & 63;
  int kgrp = l >> 4;

  // ---- block -> (strip it, chunk q); chunks(it) = ceil((64-it)/3), total 715 ----
  int rem = blockIdx.x, it = 0, ch;
  while (rem >= (ch = (64 - it + 2) / 3)) { rem -= ch; ++it; }
  int q = rem;
  int rowbase = it * 128;
  int cs0 = rowbase + q * 384;
  int niter = (NROWS - cs0) >> 5; if (niter > 12) niter = 12;  // always even, >=4

  for (int off = tid; off < 384; off += 256) colacc[off] = 0.f;

  // ---- staging: 32 reps-rows x 512B -> 16KB buffer; linear dest, swizzled src ----
  auto stage = [&](int bufi, int colbase) {
#pragma unroll
    for (int i = 0; i < 4; ++i) {
      int c2 = w * 4 + i;            // 16 chunks of 1 KB (2 rows each)
      int lr = 2 * c2 + (l >> 5);
      int kb = ((l & 31) * 16) ^ ((lr & 7) << 4);
      gload_lds16((const char*)reps_ + (size_t)(colbase + lr) * 512 + kb,
                  (void*)&smem[bufi][c2 * 64]);
    }
  };
  stage(0, cs0);
  stage(1, cs0 + 32);

  // ---- A fragments: wave w owns rows rowbase+32w..+32 ----
  bf16x8 a[2][8];
  int arow = rowbase + w * 32 + (l & 15);
#pragma unroll
  for (int fr = 0; fr < 2; ++fr) {
    const uint4* base = reps4 + (size_t)(arow + fr * 16) * 32 + kgrp;
#pragma unroll
    for (int kk = 0; kk < 8; ++kk)
      a[fr][kk] = __builtin_bit_cast(bf16x8, base[kk * 4]);
  }

  // ---- precomputed per-kk LDS byte offsets (within one 16KB buffer) ----
  int lds_a[8];
  {
    int lr0 = l & 15;
    int swz = (lr0 & 7) << 4;
#pragma unroll
    for (int kk = 0; kk < 8; ++kk)
      lds_a[kk] = lr0 * 512 + ((kk * 64 + kgrp * 16) ^ swz);
  }

  float rowsum[2][4];
#pragma unroll
  for (int fr = 0; fr < 2; ++fr)
#pragma unroll
    for (int r = 0; r < 4; ++r) rowsum[fr][r] = 0.f;

  int r0 = rowbase + w * 32 + kgrp * 4;

  // ---- epilogue on a finished acc set (registers only + LDS-atomic colacc) ----
  auto epi = [&](f32x4 (&acc)[2][2], int t) {
    int cb = cs0 + 32 * t;
    bool docol = !(q == 0 && t < 4);        // diag 128-col window: rowsum only
    bool dopos = (q == 10) && (t >= 8) && (it < 32);
    float cp0 = 0.f, cp1 = 0.f;
    int cbase = cb + (l & 15);
#pragma unroll
    for (int fr = 0; fr < 2; ++fr)
#pragma unroll
      for (int fc = 0; fc < 2; ++fc)
#pragma unroll
        for (int r = 0; r < 4; ++r) {
          int rg = r0 + fr * 16 + r;
          int cg = cbase + fc * 16;
          float s = acc[fr][fc][r];
          float e = __builtin_amdgcn_exp2f(s);
          e = (rg == cg) ? 0.f : e;
          if (dopos && cg == rg + BROWS) pos[rg] = s;
          rowsum[fr][r] += e;
          if (fc == 0) cp0 += e; else cp1 += e;
        }
    if (docol) {
      cp0 += __shfl_xor(cp0, 16, 64); cp0 += __shfl_xor(cp0, 32, 64);
      cp1 += __shfl_xor(cp1, 16, 64); cp1 += __shfl_xor(cp1, 32, 64);
      if (l < 16) {
        atomicAdd(&colacc[(cb - cs0) + l], cp0);
        atomicAdd(&colacc[(cb - cs0) + l + 16], cp1);
      }
    }
  };

  // ---- one step: wait stage(t) -> barrier -> issue stage(t+2) -> MFMA(t)
  //      into cur, with epilogue of prv overlapping the MFMA cluster ----
  auto step = [&](int t, f32x4 (&cur)[2][2], f32x4 (&prv)[2][2], bool doPrev) {
    if (t + 1 < niter) asm volatile("s_waitcnt vmcnt(4)" ::: "memory");
    else               asm volatile("s_waitcnt vmcnt(0)" ::: "memory");
    __builtin_amdgcn_sched_barrier(0);
    __builtin_amdgcn_s_barrier();        // everyone's stage(t) landed; all reads
    __builtin_amdgcn_sched_barrier(0);   // of buf[(t-1)%3] finished (prev iter)
    if (t + 2 < niter) stage((t + 2) % 3, cs0 + 32 * (t + 2));
    const char* bb = (const char*)&smem[0][0] + (t % 3) * 16384;
    const f32x4 zero = {0.f, 0.f, 0.f, 0.f};
    __builtin_amdgcn_s_setprio(1);
#pragma unroll
    for (int kk = 0; kk < 8; ++kk) {
      bf16x8 b0 = *(const bf16x8*)(bb + lds_a[kk]);
      bf16x8 b1 = *(const bf16x8*)(bb + lds_a[kk] + 8192);  // row +16, same swizzle
#pragma unroll
      for (int fr = 0; fr < 2; ++fr) {
        if (kk == 0) {
          cur[fr][0] = __builtin_amdgcn_mfma_f32_16x16x32_bf16(a[fr][0], b0, zero, 0, 0, 0);
          cur[fr][1] = __builtin_amdgcn_mfma_f32_16x16x32_bf16(a[fr][0], b1, zero, 0, 0, 0);
        } else {
          cur[fr][0] = __builtin_amdgcn_mfma_f32_16x16x32_bf16(a[fr][kk], b0, cur[fr][0], 0, 0, 0);
          cur[fr][1] = __builtin_amdgcn_mfma_f32_16x16x32_bf16(a[fr][kk], b1, cur[fr][1], 0, 0, 0);
        }
      }
    }
    __builtin_amdgcn_s_setprio(0);
    if (doPrev) epi(prv, t - 1);         // overlaps: no deps on cur/ds_reads
  };

  f32x4 accA[2][2], accB[2][2];
  for (int t = 0; t < niter; t += 2) {   // niter always even
    step(t,     accA, accB, t > 0);
    step(t + 1, accB, accA, true);
  }
  epi(accB, niter - 1);

  // ---- row sums: reduce 16 col-lanes; 4 lanes atomic per wave ----
#pragma unroll
  for (int fr = 0; fr < 2; ++fr)
#pragma unroll
    for (int r = 0; r < 4; ++r) {
      float v = rowsum[fr][r];
      v += __shfl_xor(v, 1, 64);
      v += __shfl_xor(v, 2, 64);
      v += __shfl_xor(v, 4, 64);
      v += __shfl_xor(v, 8, 64);
      if ((l & 15) == 0) atomicAdd(&denom[r0 + fr * 16 + r], v);
    }

  // ---- col sums: flush colacc, one atomic per column ----
  __syncthreads();
  for (int off = tid; off < 384; off += 256) {
    float v = colacc[off];
    int col = cs0 + off;
    if (col < NROWS && v != 0.f) atomicAdd(&denom[col], v);
  }
}

// Kernel F: + (1/N) * sum_i (log(denom_i) - posS_{i mod B} * ln2)
__global__ __launch_bounds__(256) void kfin(const float* __restrict__ denom,
                                            const float* __restrict__ pos,
                                            float* __restrict__ out) {
  int i = blockIdx.x * 256 + threadIdx.x;
  float v = (logf(denom[i]) - pos[i & 4095] * LN2) * (1.0f / 8192.0f);
#pragma unroll
  for (int m = 1; m < 64; m <<= 1) v += __shfl_xor(v, m, 64);
  __shared__ float part[4];
  if ((threadIdx.x & 63) == 0) part[threadIdx.x >> 6] = v;
  __syncthreads();
  if (threadIdx.x == 0)
    atomicAdd(out, part[0] + part[1] + part[2] + part[3]);
}

extern "C" void kernel_launch(void* const* d_in, const int* in_sizes, int n_in,
                              void* d_out, int out_size, void* d_ws, size_t ws_size,
                              hipStream_t stream) {
  (void)in_sizes; (void)n_in; (void)out_size; (void)ws_size;
  const float* zi = (const float*)d_in[0];
  const float* zj = (const float*)d_in[1];
  float* out = (float*)d_out;
  char* ws = (char*)d_ws;
  unsigned short* reps = (unsigned short*)ws;                 // 4 MB
  float* denom = (float*)(ws + 4194304);                      // 32 KB
  float* pos   = (float*)(ws + 4194304 + 32768);              // 16 KB

  knorm<<<2048, 256, 0, stream>>>(zi, zj, reps, denom, out);
  ksim<<<NBLK, 256, 0, stream>>>(reps, denom, pos);
  kfin<<<32, 256, 0, stream>>>(denom, pos, out);
}